// Round 8
// baseline (706.069 us; speedup 1.0000x reference)
//
#include <hip/hip_runtime.h>
#include <hip/hip_bf16.h>

typedef unsigned short u16;
typedef unsigned int   u32;
typedef unsigned long long u64;

// N=50000, F=64, H=128, HEADS=4, C=32, L=3, E=800000, G=512, DG=32, NC=1
// Float I/O is FLOAT32; internal node features h/hh are bf16 for MFMA.
#define HD 128
#define FD 64
#define EPS 1e-5f
#define BSH 8
#define CAP 8192   // per-bucket arena capacity (bucket mean ~4082, max ~4350)

using bf16x8 = __attribute__((ext_vector_type(8))) short;
using f32x4  = __attribute__((ext_vector_type(4))) float;

__device__ __forceinline__ float b2f(u16 v) { return __uint_as_float(((u32)v) << 16); }
__device__ __forceinline__ u16 f2b(float f) {
    u32 u = __float_as_uint(f);
    return (u16)((u + 0x7FFF + ((u >> 16) & 1)) >> 16);  // RNE
}
__device__ __forceinline__ float lo16(u32 u) { return __uint_as_float(u << 16); }
__device__ __forceinline__ float hi16(u32 u) { return __uint_as_float(u & 0xFFFF0000u); }

// ---------------- prep: wprep (y<4) + gbound (y==4) + zeroing (y==5) ----------------
__global__ __launch_bounds__(256) void k_prep(
    const float* __restrict__ node_w, const float* __restrict__ gat_lin,
    u16* __restrict__ wf_node, u16* __restrict__ wf_gat,
    const int* __restrict__ batch, int* __restrict__ gs,
    int* __restrict__ zbase, int zn, int N, int G) {
    int y = blockIdx.y;
    int tid = threadIdx.x;
    if (y < 4) {
        const float* src; u16* dst; int K;
        if (y == 0) { src = node_w; dst = wf_node; K = FD; }
        else { src = gat_lin + (size_t)(y - 1) * HD * HD; dst = wf_gat + (size_t)(y - 1) * HD * HD; K = HD; }
        int KT = K >> 5;
        int total = K * HD;
        for (int f = blockIdx.x * 256 + tid; f < total; f += gridDim.x * 256) {
            int j = f & 7;
            int lane = (f >> 3) & 63;
            int t = f >> 9;           // ct*KT + kt
            int kt = t % KT;
            int ct = t / KT;
            int k = kt * 32 + (lane >> 4) * 8 + j;
            int col = ct * 16 + (lane & 15);
            dst[f] = f2b(src[k * HD + col]);
        }
    } else if (y == 4) {
        int i = blockIdx.x * 256 + tid;
        if (i < N) {
            int b = batch[i];
            if (i == 0) { for (int g = 0; g <= b; g++) gs[g] = 0; }
            else {
                int pb = batch[i - 1];
                for (int g = pb + 1; g <= b; g++) gs[g] = i;
            }
            if (i == N - 1) { for (int g = b + 1; g <= G; g++) gs[g] = N; }
        }
    } else {
        for (int i = blockIdx.x * 256 + tid; i < zn; i += gridDim.x * 256) zbase[i] = 0;
    }
}

// ---------------- binA (hist + bucket-sort into arena) ∪ node encoder MFMA ----------------
__global__ __launch_bounds__(256) void k_binA_node(
    const int* __restrict__ src, const int* __restrict__ dst,
    int* __restrict__ cnt, int* __restrict__ bcur, u64* __restrict__ arena,
    const float* __restrict__ x, const u16* __restrict__ wf, const float* __restrict__ bias,
    const float* __restrict__ g, const float* __restrict__ bb, const float* __restrict__ m,
    const float* __restrict__ v, u16* __restrict__ h,
    int E, int NB, int numTiles, int N) {
    __shared__ __align__(16) char smem[4096 * 8 + 4 * 256 * 4];   // 36 KB
    int tid = threadIdx.x;
    if ((int)blockIdx.x < numTiles) {
        // ---- binA: one 4096-edge tile ----
        u32* os   = (u32*)smem;
        u32* od   = os + 4096;
        int* hist = (int*)(od + 4096);
        int* obas = hist + 256;
        int* ofs  = obas + 256;
        int* gpos = ofs + 256;
        int base = blockIdx.x * 4096;
        int cntE = E - base; if (cntE > 4096) cntE = 4096;
        hist[tid] = 0;
        __syncthreads();
        u32 rs[16], rd[16];
        #pragma unroll
        for (int r = 0; r < 16; r++) {
            int li = r * 256 + tid;
            if (li < cntE) {
                rs[r] = src[base + li];
                rd[r] = dst[base + li];
                atomicAdd(&hist[rd[r] >> BSH], 1);
                atomicAdd(&cnt[rd[r]], 1);          // fused k_hist
            }
        }
        __syncthreads();
        if (tid < 64) {
            int h0 = hist[4 * tid], h1 = hist[4 * tid + 1];
            int h2 = hist[4 * tid + 2], h3 = hist[4 * tid + 3];
            int s01 = h0 + h1;
            int loc = s01 + h2 + h3;
            int inc = loc;
            #pragma unroll
            for (int off = 1; off < 64; off <<= 1) {
                int tv = __shfl_up(inc, off);
                if (tid >= off) inc += tv;
            }
            int excl = inc - loc;
            obas[4 * tid] = excl;                 ofs[4 * tid] = excl;
            obas[4 * tid + 1] = excl + h0;        ofs[4 * tid + 1] = excl + h0;
            obas[4 * tid + 2] = excl + s01;       ofs[4 * tid + 2] = excl + s01;
            obas[4 * tid + 3] = excl + s01 + h2;  ofs[4 * tid + 3] = excl + s01 + h2;
        }
        __syncthreads();
        #pragma unroll
        for (int r = 0; r < 16; r++) {
            int li = r * 256 + tid;
            if (li < cntE) {
                int b = rd[r] >> BSH;
                int posn = atomicAdd(&ofs[b], 1);
                os[posn] = rs[r];
                od[posn] = rd[r];
            }
        }
        __syncthreads();
        if (tid < NB && hist[tid] > 0)
            gpos[tid] = atomicAdd(&bcur[tid], hist[tid]);
        __syncthreads();
        for (int li = tid; li < cntE; li += 256) {
            u32 d = od[li];
            int b = d >> BSH;
            int p = gpos[b] + (li - obas[b]);
            if (p < CAP) arena[(size_t)b * CAP + p] = ((u64)d << 32) | os[li];
        }
    } else {
        // ---- node encoder: h = relu(bn(x @ W + b)) via MFMA ----
        int nb = blockIdx.x - numTiles;
        int wv = tid >> 6, lane = tid & 63;
        int rowbase = nb * 64 + wv * 16;
        if (rowbase >= N) return;
        int n16 = lane & 15, quad = lane >> 4;
        int arow = min(rowbase + n16, N - 1);
        f32x4 acc[8] = {};
        #pragma unroll
        for (int kt = 0; kt < 2; kt++) {
            const float4* xp = (const float4*)(x + (size_t)arow * FD + kt * 32 + quad * 8);
            float4 a0 = xp[0], a1 = xp[1];
            bf16x8 a;
            a[0] = (short)f2b(a0.x); a[1] = (short)f2b(a0.y);
            a[2] = (short)f2b(a0.z); a[3] = (short)f2b(a0.w);
            a[4] = (short)f2b(a1.x); a[5] = (short)f2b(a1.y);
            a[6] = (short)f2b(a1.z); a[7] = (short)f2b(a1.w);
            #pragma unroll
            for (int ct = 0; ct < 8; ct++) {
                bf16x8 b = *(const bf16x8*)(wf + ((size_t)(ct * 2 + kt) * 64 + lane) * 8);
                acc[ct] = __builtin_amdgcn_mfma_f32_16x16x32_bf16(a, b, acc[ct], 0, 0, 0);
            }
        }
        #pragma unroll
        for (int ct = 0; ct < 8; ct++) {
            int col = ct * 16 + n16;
            float sc = g[col] * rsqrtf(v[col] + EPS);
            float bi = (bias[col] - m[col]) * sc + bb[col];
            #pragma unroll
            for (int reg = 0; reg < 4; reg++) {
                int row = rowbase + quad * 4 + reg;
                if (row < N) h[(size_t)row * HD + col] = f2b(fmaxf(acc[ct][reg] * sc + bi, 0.f));
            }
        }
    }
}

// ---------------- fused scan (single-pass lookback) + binB scatter ----------------
__global__ __launch_bounds__(256) void k_scanB2(
    const int* __restrict__ cnt, int* __restrict__ rowptr,
    const u64* __restrict__ arena, const int* __restrict__ bcur,
    int* __restrict__ colidx, int* __restrict__ ready, int* __restrict__ bval, int N) {
    __shared__ int rowL[256], lofs[256], cL[256];
    __shared__ int stot, sbase;
    int b = blockIdx.x, tid = threadIdx.x;
    int n0 = b << BSH;
    int n = n0 + tid;
    cL[tid] = (n < N) ? cnt[n] : 0;
    __syncthreads();
    if (tid < 64) {
        int h0 = cL[4 * tid], h1 = cL[4 * tid + 1];
        int h2 = cL[4 * tid + 2], h3 = cL[4 * tid + 3];
        int s01 = h0 + h1;
        int loc = s01 + h2 + h3;
        int inc = loc;
        #pragma unroll
        for (int off = 1; off < 64; off <<= 1) {
            int tv = __shfl_up(inc, off);
            if (tid >= off) inc += tv;
        }
        int excl = inc - loc;
        rowL[4 * tid] = excl;
        rowL[4 * tid + 1] = excl + h0;
        rowL[4 * tid + 2] = excl + s01;
        rowL[4 * tid + 3] = excl + s01 + h2;
        if (tid == 63) stot = inc;
    }
    __syncthreads();
    int total = stot;
    if (tid == 0) {
        int basev = 0;
        if (b > 0) {
            while (atomicAdd(&ready[b - 1], 0) == 0) {}
            basev = atomicAdd(&bval[b - 1], 0);
        }
        atomicExch(&bval[b], basev + total);
        __threadfence();
        atomicExch(&ready[b], 1);
        sbase = basev;
    }
    __syncthreads();
    int basev = sbase;
    if (n < N) rowptr[n] = basev + rowL[tid];
    if (b == (int)gridDim.x - 1 && tid == 0) rowptr[N] = basev + total;
    rowL[tid] += basev;
    lofs[tid] = 0;
    __syncthreads();
    int nedge = bcur[b];
    if (nedge > CAP) nedge = CAP;
    for (int i = tid; i < nedge; i += 256) {
        u64 pk = arena[(size_t)b * CAP + i];
        int d = (int)(pk >> 32), s = (int)(pk & 0xFFFFFFFFu);
        int slot = atomicAdd(&lofs[d - n0], 1);
        colidx[rowL[d - n0] + slot] = s;
    }
}

// ---------------- GAT linear via MFMA (unchanged from R7) ----------------
__global__ __launch_bounds__(256) void k_gat_mfma(
    const u16* __restrict__ h, const u16* __restrict__ wf,
    const float* __restrict__ asrcw, const float* __restrict__ adstw,
    u16* __restrict__ hh, float* __restrict__ a_src, float* __restrict__ a_dst, int N) {
    int wv = threadIdx.x >> 6, lane = threadIdx.x & 63;
    int rowbase = blockIdx.x * 64 + wv * 16;
    if (rowbase >= N) return;
    int n16 = lane & 15, quad = lane >> 4;
    int arow = min(rowbase + n16, N - 1);
    f32x4 acc[8] = {};
    #pragma unroll
    for (int kt = 0; kt < 4; kt++) {
        bf16x8 a = *(const bf16x8*)(h + (size_t)arow * HD + kt * 32 + quad * 8);
        #pragma unroll
        for (int ct = 0; ct < 8; ct++) {
            bf16x8 b = *(const bf16x8*)(wf + ((size_t)(ct * 4 + kt) * 64 + lane) * 8);
            acc[ct] = __builtin_amdgcn_mfma_f32_16x16x32_bf16(a, b, acc[ct], 0, 0, 0);
        }
    }
    float asw[8], adw[8];
    #pragma unroll
    for (int ct = 0; ct < 8; ct++) {
        asw[ct] = asrcw[ct * 16 + n16];
        adw[ct] = adstw[ct * 16 + n16];
    }
    float ps[4][4], pd[4][4];
    #pragma unroll
    for (int hd = 0; hd < 4; hd++)
        #pragma unroll
        for (int reg = 0; reg < 4; reg++) {
            ps[hd][reg] = acc[2 * hd][reg] * asw[2 * hd] + acc[2 * hd + 1][reg] * asw[2 * hd + 1];
            pd[hd][reg] = acc[2 * hd][reg] * adw[2 * hd] + acc[2 * hd + 1][reg] * adw[2 * hd + 1];
        }
    #pragma unroll
    for (int msk = 1; msk < 16; msk <<= 1) {
        #pragma unroll
        for (int hd = 0; hd < 4; hd++)
            #pragma unroll
            for (int reg = 0; reg < 4; reg++) {
                ps[hd][reg] += __shfl_xor(ps[hd][reg], msk);
                pd[hd][reg] += __shfl_xor(pd[hd][reg], msk);
            }
    }
    #pragma unroll
    for (int reg = 0; reg < 4; reg++) {
        int row = rowbase + quad * 4 + reg;
        if (row < N) {
            #pragma unroll
            for (int ct = 0; ct < 8; ct++)
                hh[(size_t)row * HD + ct * 16 + n16] = f2b(acc[ct][reg]);
            if (n16 < 4) {
                float ws = 0.f, wd = 0.f;
                #pragma unroll
                for (int hd = 0; hd < 4; hd++)
                    if (n16 == hd) { ws = ps[hd][reg]; wd = pd[hd][reg]; }
                a_src[row * 4 + n16] = ws;
                a_dst[row * 4 + n16] = wd;
            }
        }
    }
}

// ---------------- per-node attention aggregation: 8-wide batched gather (R7) ----------------
__global__ __launch_bounds__(256) void k_agg(
    u16* __restrict__ h, const u32* __restrict__ hh32,
    const float* __restrict__ a_src, const float* __restrict__ a_dst,
    const int* __restrict__ rowptr, const int* __restrict__ colidx,
    const float* __restrict__ bias, const float* __restrict__ bng, const float* __restrict__ bnb,
    const float* __restrict__ bnm, const float* __restrict__ bnv, int N) {
    __shared__ int   sL[4][64];
    __shared__ __align__(16) float eeL[4][64][4];
    int wv = threadIdx.x >> 6, lane = threadIdx.x & 63;
    int node = blockIdx.x * 4 + wv;
    if (node >= N) return;
    int head = lane >> 4;
    const float4* as4p = (const float4*)a_src;
    float4 ad4 = ((const float4*)a_dst)[node];
    float adh = (head == 0) ? ad4.x : (head == 1) ? ad4.y : (head == 2) ? ad4.z : ad4.w;
    float ash = a_src[node * 4 + head];
    float e = ash + adh;
    e = (e > 0.f) ? e : 0.2f * e;
    float ee = __expf(e);
    float den = ee;
    u32 hv = hh32[(size_t)node * 64 + lane];
    float acc0 = ee * lo16(hv), acc1 = ee * hi16(hv);
    int beg = rowptr[node], end = rowptr[node + 1];
    for (int base = beg; base < end; base += 64) {
        int cnt = end - base; if (cnt > 64) cnt = 64;
        int s = 0;
        float4 e4 = {0.f, 0.f, 0.f, 0.f};
        if (lane < cnt) {
            s = colidx[base + lane];
            float4 as4 = as4p[s];
            float t0 = as4.x + ad4.x, t1 = as4.y + ad4.y, t2 = as4.z + ad4.z, t3 = as4.w + ad4.w;
            t0 = (t0 > 0.f) ? t0 : 0.2f * t0; t1 = (t1 > 0.f) ? t1 : 0.2f * t1;
            t2 = (t2 > 0.f) ? t2 : 0.2f * t2; t3 = (t3 > 0.f) ? t3 : 0.2f * t3;
            e4.x = __expf(t0); e4.y = __expf(t1); e4.z = __expf(t2); e4.w = __expf(t3);
        }
        sL[wv][lane] = s;
        ((float4*)eeL[wv][lane])[0] = e4;
        int j = 0;
        for (; j + 8 <= cnt; j += 8) {
            u32 hv2[8]; float w[8];
            #pragma unroll
            for (int q = 0; q < 8; q++) {
                int sj = sL[wv][j + q];
                w[q] = eeL[wv][j + q][head];
                hv2[q] = hh32[(size_t)sj * 64 + lane];
            }
            #pragma unroll
            for (int q = 0; q < 8; q++) {
                den += w[q];
                acc0 += w[q] * lo16(hv2[q]);
                acc1 += w[q] * hi16(hv2[q]);
            }
        }
        for (; j < cnt; j++) {
            int sj = sL[wv][j];
            float w = eeL[wv][j][head];
            u32 hv2 = hh32[(size_t)sj * 64 + lane];
            den += w;
            acc0 += w * lo16(hv2);
            acc1 += w * hi16(hv2);
        }
    }
    float inv = 1.0f / (den + 1e-16f);
    int c0 = lane * 2, c1 = c0 + 1;
    float o0 = acc0 * inv, o1 = acc1 * inv;
    float sc0 = bng[c0] * rsqrtf(bnv[c0] + EPS);
    float sc1 = bng[c1] * rsqrtf(bnv[c1] + EPS);
    o0 = (o0 + bias[c0] - bnm[c0]) * sc0 + bnb[c0];
    o1 = (o1 + bias[c1] - bnm[c1]) * sc1 + bnb[c1];
    o0 = fmaxf(o0, 0.f); o1 = fmaxf(o1, 0.f);
    u32 idv = ((const u32*)h)[(size_t)node * 64 + lane];
    o0 += lo16(idv); o1 += hi16(idv);
    ((u32*)h)[(size_t)node * 64 + lane] = ((u32)f2b(o1) << 16) | f2b(o0);
}

// ---------------- fused readout: pool + glob + lin1 + lin2 (8 graphs/block) ----------------
__global__ __launch_bounds__(256) void k_readout(
    const u16* __restrict__ h, const int* __restrict__ gs,
    const float* __restrict__ gf, const float* __restrict__ glob_w, const float* __restrict__ glob_b,
    const float* __restrict__ gbg, const float* __restrict__ gbb,
    const float* __restrict__ gbm, const float* __restrict__ gbv,
    const float* __restrict__ W1, const float* __restrict__ b1,
    const float* __restrict__ W2, const float* __restrict__ b2,
    float* __restrict__ out, int N, int G) {
    __shared__ float zL[8][384];    // 12 KB
    __shared__ float Wc[64][128];   // 32 KB (also pool scratch)
    __shared__ float red[8][128];   // 4 KB
    int tid = threadIdx.x;
    int g0 = blockIdx.x * 8;
    int c = tid & 127, half = tid >> 7;
    float* scratch = &Wc[0][0];
    // pool: mean/max per graph
    for (int gi = 0; gi < 8; gi++) {
        int g = g0 + gi;
        float s = 0.f, mx = -3.4e38f;
        int beg = 0, end = 0;
        if (g < G) {
            beg = gs[g]; end = gs[g + 1];
            for (int r = beg + half; r < end; r += 2) {
                float vv = b2f(h[(size_t)r * HD + c]);
                s += vv; mx = fmaxf(mx, vv);
            }
        }
        if (half == 1) { scratch[c] = s; scratch[128 + c] = mx; }
        __syncthreads();
        if (half == 0) {
            s += scratch[c]; mx = fmaxf(mx, scratch[128 + c]);
            int cn = end - beg;
            zL[gi][c] = s / (float)(cn > 0 ? cn : 1);
            zL[gi][128 + c] = (cn == 0) ? 0.f : mx;
        }
        __syncthreads();
    }
    // glob encoder: each half handles 4 graphs
    {
        float sc = gbg[c] * rsqrtf(gbv[c] + EPS);
        float gb0 = glob_b[c], gm = gbm[c], gbb_ = gbb[c];
        for (int q = 0; q < 4; q++) {
            int gi = half * 4 + q;
            int g = g0 + gi;
            float acc = gb0;
            if (g < G) {
                #pragma unroll 8
                for (int k = 0; k < 32; k++) acc += gf[g * 32 + k] * glob_w[k * HD + c];
                acc = (acc - gm) * sc + gbb_;
                zL[gi][256 + c] = fmaxf(acc, 0.f);
            } else {
                zL[gi][256 + c] = 0.f;
            }
        }
    }
    __syncthreads();
    // lin1 + lin2 (LDS-staged W1 chunks)
    float acc0 = 0.f, acc1 = 0.f, acc2 = 0.f, acc3 = 0.f;
    int gb = half * 4;
    for (int ch = 0; ch < 6; ch++) {
        __syncthreads();
        for (int i4 = tid; i4 < 2048; i4 += 256) {
            int flat = i4 * 4;
            int k = flat >> 7, cc = flat & 127;
            *(float4*)&Wc[k][cc] = *(const float4*)&W1[(size_t)(ch * 64 + k) * HD + cc];
        }
        __syncthreads();
        int kb = ch * 64;
        #pragma unroll 4
        for (int k = 0; k < 64; k++) {
            float w = Wc[k][c];
            acc0 += zL[gb + 0][kb + k] * w;
            acc1 += zL[gb + 1][kb + k] * w;
            acc2 += zL[gb + 2][kb + k] * w;
            acc3 += zL[gb + 3][kb + k] * w;
        }
    }
    float b1c = b1[c], w2c = W2[c];
    __syncthreads();
    red[gb + 0][c] = fmaxf(acc0 + b1c, 0.f) * w2c;
    red[gb + 1][c] = fmaxf(acc1 + b1c, 0.f) * w2c;
    red[gb + 2][c] = fmaxf(acc2 + b1c, 0.f) * w2c;
    red[gb + 3][c] = fmaxf(acc3 + b1c, 0.f) * w2c;
    __syncthreads();
    int gr = tid >> 5, l32 = tid & 31;
    float v = red[gr][l32] + red[gr][l32 + 32] + red[gr][l32 + 64] + red[gr][l32 + 96];
    #pragma unroll
    for (int mk = 1; mk < 32; mk <<= 1) v += __shfl_xor(v, mk, 32);
    if (l32 == 0 && g0 + gr < G) out[g0 + gr] = v + b2[0];
}

extern "C" void kernel_launch(void* const* d_in, const int* in_sizes, int n_in,
                              void* d_out, int out_size, void* d_ws, size_t ws_size,
                              hipStream_t stream) {
    (void)n_in; (void)out_size; (void)ws_size;
    const float* x        = (const float*)d_in[0];
    const float* gfeat    = (const float*)d_in[2];
    const int*   ei       = (const int*)d_in[3];
    const int*   batch    = (const int*)d_in[4];
    const float* node_w   = (const float*)d_in[5];
    const float* node_b   = (const float*)d_in[6];
    const float* nbg      = (const float*)d_in[7];
    const float* nbb      = (const float*)d_in[8];
    const float* nbm      = (const float*)d_in[9];
    const float* nbv      = (const float*)d_in[10];
    const float* glob_w   = (const float*)d_in[13];
    const float* glob_b   = (const float*)d_in[14];
    const float* gbg      = (const float*)d_in[15];
    const float* gbb      = (const float*)d_in[16];
    const float* gbm      = (const float*)d_in[17];
    const float* gbv      = (const float*)d_in[18];
    const float* gat_lin  = (const float*)d_in[19];
    const float* gat_asrc = (const float*)d_in[20];
    const float* gat_adst = (const float*)d_in[21];
    const float* gat_bias = (const float*)d_in[22];
    const float* bn_g     = (const float*)d_in[23];
    const float* bn_b     = (const float*)d_in[24];
    const float* bn_m     = (const float*)d_in[25];
    const float* bn_v     = (const float*)d_in[26];
    const float* lin1_w   = (const float*)d_in[27];
    const float* lin1_b   = (const float*)d_in[28];
    const float* lin2_w   = (const float*)d_in[29];
    const float* lin2_b   = (const float*)d_in[30];

    const int N = in_sizes[0] / FD;
    const int E = in_sizes[3] / 2;
    const int G = in_sizes[2] / 32;
    const int* srcp = ei;
    const int* dstp = ei + E;
    const int NB = (N + 255) >> BSH;          // 196 for N=50000 (requires NB <= 256)
    const int numTiles = (E + 4095) / 4096;   // 196

    char* p = (char*)d_ws;
    auto alloc = [&](size_t bytes) -> char* {
        char* r = p;
        p += (bytes + 255) & ~(size_t)255;
        return r;
    };
    u16*   h       = (u16*)alloc((size_t)N * HD * 2);
    u16*   hh      = (u16*)alloc((size_t)N * HD * 2);
    float* a_src   = (float*)alloc((size_t)N * 4 * 4);
    float* a_dst   = (float*)alloc((size_t)N * 4 * 4);
    int*   rowptr  = (int*)alloc((size_t)(N + 1) * 4);
    char*  zbase   = p;                        // cnt, bcur, ready zeroed by k_prep
    int*   cnt     = (int*)alloc((size_t)N * 4);
    int*   bcur    = (int*)alloc(256 * 4);
    int*   ready   = (int*)alloc(256 * 4);
    int    zn      = (int)((p - zbase) / 4);
    int*   bval    = (int*)alloc(256 * 4);
    u64*   arena   = (u64*)alloc((size_t)NB * CAP * 8);
    int*   colidx  = (int*)alloc((size_t)E * 4);
    u16*   wf_node = (u16*)alloc((size_t)FD * HD * 2);
    u16*   wf_gat  = (u16*)alloc((size_t)3 * HD * HD * 2);
    int*   gs      = (int*)alloc((size_t)(G + 1) * 4);

    int SB = (N + 255) / 256;   // 196

    // D1: weight prep + graph bounds + zeroing
    k_prep<<<dim3(SB, 6), 256, 0, stream>>>(node_w, gat_lin, wf_node, wf_gat,
                                            batch, gs, (int*)zbase, zn, N, G);
    // D2: bucket-sort edges (+hist) ∪ node encoder
    int nodeBlocks = (N + 63) / 64;
    k_binA_node<<<numTiles + nodeBlocks, 256, 0, stream>>>(
        srcp, dstp, cnt, bcur, arena,
        x, wf_node, node_b, nbg, nbb, nbm, nbv, h,
        E, NB, numTiles, N);
    // D3: single-pass scan + bucket scatter -> rowptr, colidx
    k_scanB2<<<NB, 256, 0, stream>>>(cnt, rowptr, arena, bcur, colidx, ready, bval, N);

    // D4-D9: GAT layers
    for (int i = 0; i < 3; i++) {
        k_gat_mfma<<<(N + 63) / 64, 256, 0, stream>>>(
            h, wf_gat + (size_t)i * HD * HD,
            gat_asrc + i * HD, gat_adst + i * HD,
            hh, a_src, a_dst, N);
        k_agg<<<(N + 3) / 4, 256, 0, stream>>>(
            h, (const u32*)hh, a_src, a_dst, rowptr, colidx,
            gat_bias + i * HD, bn_g + i * HD, bn_b + i * HD, bn_m + i * HD, bn_v + i * HD, N);
    }

    // D10: fused readout
    k_readout<<<(G + 7) / 8, 256, 0, stream>>>(h, gs, gfeat, glob_w, glob_b, gbg, gbb, gbm, gbv,
                                               lin1_w, lin1_b, lin2_w, lin2_b, (float*)d_out, N, G);
}

// Round 9
// 403.079 us; speedup vs baseline: 1.7517x; 1.7517x over previous
//
#include <hip/hip_runtime.h>
#include <hip/hip_bf16.h>

typedef unsigned short u16;
typedef unsigned int   u32;
typedef unsigned long long u64;

// N=50000, F=64, H=128, HEADS=4, C=32, L=3, E=800000, G=512, DG=32, NC=1
// Float I/O is FLOAT32; internal node features h/hh are bf16 for MFMA.
#define HD 128
#define FD 64
#define EPS 1e-5f
#define BSH 8
#define CAP 8192   // per-bucket arena capacity (bucket mean ~4082, max ~4350)

using bf16x8 = __attribute__((ext_vector_type(8))) short;
using f32x4  = __attribute__((ext_vector_type(4))) float;

__device__ __forceinline__ float b2f(u16 v) { return __uint_as_float(((u32)v) << 16); }
__device__ __forceinline__ u16 f2b(float f) {
    u32 u = __float_as_uint(f);
    return (u16)((u + 0x7FFF + ((u >> 16) & 1)) >> 16);  // RNE
}
__device__ __forceinline__ float lo16(u32 u) { return __uint_as_float(u << 16); }
__device__ __forceinline__ float hi16(u32 u) { return __uint_as_float(u & 0xFFFF0000u); }

// ---------------- prep: wprep (y<4) + gbound (y==4) + zeroing (y==5) ----------------
__global__ __launch_bounds__(256) void k_prep(
    const float* __restrict__ node_w, const float* __restrict__ gat_lin,
    u16* __restrict__ wf_node, u16* __restrict__ wf_gat,
    const int* __restrict__ batch, int* __restrict__ gs,
    int* __restrict__ zbase, int zn, int N, int G) {
    int y = blockIdx.y;
    int tid = threadIdx.x;
    if (y < 4) {
        const float* src; u16* dst; int K;
        if (y == 0) { src = node_w; dst = wf_node; K = FD; }
        else { src = gat_lin + (size_t)(y - 1) * HD * HD; dst = wf_gat + (size_t)(y - 1) * HD * HD; K = HD; }
        int KT = K >> 5;
        int total = K * HD;
        for (int f = blockIdx.x * 256 + tid; f < total; f += gridDim.x * 256) {
            int j = f & 7;
            int lane = (f >> 3) & 63;
            int t = f >> 9;           // ct*KT + kt
            int kt = t % KT;
            int ct = t / KT;
            int k = kt * 32 + (lane >> 4) * 8 + j;
            int col = ct * 16 + (lane & 15);
            dst[f] = f2b(src[k * HD + col]);
        }
    } else if (y == 4) {
        int i = blockIdx.x * 256 + tid;
        if (i < N) {
            int b = batch[i];
            if (i == 0) { for (int g = 0; g <= b; g++) gs[g] = 0; }
            else {
                int pb = batch[i - 1];
                for (int g = pb + 1; g <= b; g++) gs[g] = i;
            }
            if (i == N - 1) { for (int g = b + 1; g <= G; g++) gs[g] = N; }
        }
    } else {
        for (int i = blockIdx.x * 256 + tid; i < zn; i += gridDim.x * 256) zbase[i] = 0;
    }
}

// ---------------- binA (hist + bucket-sort into arena) ∪ node encoder MFMA ----------------
__global__ __launch_bounds__(256) void k_binA_node(
    const int* __restrict__ src, const int* __restrict__ dst,
    int* __restrict__ cnt, int* __restrict__ bcur, u64* __restrict__ arena,
    const float* __restrict__ x, const u16* __restrict__ wf, const float* __restrict__ bias,
    const float* __restrict__ g, const float* __restrict__ bb, const float* __restrict__ m,
    const float* __restrict__ v, u16* __restrict__ h,
    int E, int NB, int numTiles, int N) {
    __shared__ __align__(16) char smem[4096 * 8 + 4 * 256 * 4];   // 36 KB
    int tid = threadIdx.x;
    if ((int)blockIdx.x < numTiles) {
        // ---- binA: one 4096-edge tile ----
        u32* os   = (u32*)smem;
        u32* od   = os + 4096;
        int* hist = (int*)(od + 4096);
        int* obas = hist + 256;
        int* ofs  = obas + 256;
        int* gpos = ofs + 256;
        int base = blockIdx.x * 4096;
        int cntE = E - base; if (cntE > 4096) cntE = 4096;
        hist[tid] = 0;
        __syncthreads();
        u32 rs[16], rd[16];
        #pragma unroll
        for (int r = 0; r < 16; r++) {
            int li = r * 256 + tid;
            if (li < cntE) {
                rs[r] = src[base + li];
                rd[r] = dst[base + li];
                atomicAdd(&hist[rd[r] >> BSH], 1);
                atomicAdd(&cnt[rd[r]], 1);          // fused k_hist
            }
        }
        __syncthreads();
        if (tid < 64) {
            int h0 = hist[4 * tid], h1 = hist[4 * tid + 1];
            int h2 = hist[4 * tid + 2], h3 = hist[4 * tid + 3];
            int s01 = h0 + h1;
            int loc = s01 + h2 + h3;
            int inc = loc;
            #pragma unroll
            for (int off = 1; off < 64; off <<= 1) {
                int tv = __shfl_up(inc, off);
                if (tid >= off) inc += tv;
            }
            int excl = inc - loc;
            obas[4 * tid] = excl;                 ofs[4 * tid] = excl;
            obas[4 * tid + 1] = excl + h0;        ofs[4 * tid + 1] = excl + h0;
            obas[4 * tid + 2] = excl + s01;       ofs[4 * tid + 2] = excl + s01;
            obas[4 * tid + 3] = excl + s01 + h2;  ofs[4 * tid + 3] = excl + s01 + h2;
        }
        __syncthreads();
        #pragma unroll
        for (int r = 0; r < 16; r++) {
            int li = r * 256 + tid;
            if (li < cntE) {
                int b = rd[r] >> BSH;
                int posn = atomicAdd(&ofs[b], 1);
                os[posn] = rs[r];
                od[posn] = rd[r];
            }
        }
        __syncthreads();
        if (tid < NB && hist[tid] > 0)
            gpos[tid] = atomicAdd(&bcur[tid], hist[tid]);
        __syncthreads();
        for (int li = tid; li < cntE; li += 256) {
            u32 d = od[li];
            int b = d >> BSH;
            int p = gpos[b] + (li - obas[b]);
            if (p < CAP) arena[(size_t)b * CAP + p] = ((u64)d << 32) | os[li];
        }
    } else {
        // ---- node encoder: h = relu(bn(x @ W + b)) via MFMA ----
        int nb = blockIdx.x - numTiles;
        int wv = tid >> 6, lane = tid & 63;
        int rowbase = nb * 64 + wv * 16;
        if (rowbase >= N) return;
        int n16 = lane & 15, quad = lane >> 4;
        int arow = min(rowbase + n16, N - 1);
        f32x4 acc[8] = {};
        #pragma unroll
        for (int kt = 0; kt < 2; kt++) {
            const float4* xp = (const float4*)(x + (size_t)arow * FD + kt * 32 + quad * 8);
            float4 a0 = xp[0], a1 = xp[1];
            bf16x8 a;
            a[0] = (short)f2b(a0.x); a[1] = (short)f2b(a0.y);
            a[2] = (short)f2b(a0.z); a[3] = (short)f2b(a0.w);
            a[4] = (short)f2b(a1.x); a[5] = (short)f2b(a1.y);
            a[6] = (short)f2b(a1.z); a[7] = (short)f2b(a1.w);
            #pragma unroll
            for (int ct = 0; ct < 8; ct++) {
                bf16x8 b = *(const bf16x8*)(wf + ((size_t)(ct * 2 + kt) * 64 + lane) * 8);
                acc[ct] = __builtin_amdgcn_mfma_f32_16x16x32_bf16(a, b, acc[ct], 0, 0, 0);
            }
        }
        #pragma unroll
        for (int ct = 0; ct < 8; ct++) {
            int col = ct * 16 + n16;
            float sc = g[col] * rsqrtf(v[col] + EPS);
            float bi = (bias[col] - m[col]) * sc + bb[col];
            #pragma unroll
            for (int reg = 0; reg < 4; reg++) {
                int row = rowbase + quad * 4 + reg;
                if (row < N) h[(size_t)row * HD + col] = f2b(fmaxf(acc[ct][reg] * sc + bi, 0.f));
            }
        }
    }
}

// ---------------- single-block scan of bucket totals (bcur -> bbase) ----------------
__global__ __launch_bounds__(256) void k_scanS(const int* __restrict__ bcur, int* __restrict__ bbase, int NB) {
    __shared__ int s[256];
    int tid = threadIdx.x;
    int v = (tid < NB) ? bcur[tid] : 0;
    s[tid] = v;
    __syncthreads();
    for (int off = 1; off < 256; off <<= 1) {
        int t = (tid >= off) ? s[tid - off] : 0;
        __syncthreads();
        s[tid] += t;
        __syncthreads();
    }
    if (tid < NB) bbase[tid] = s[tid] - v;   // exclusive
}

// ---------------- per-bucket: local node scan -> rowptr + arena scatter -> colidx ----------
__global__ __launch_bounds__(256) void k_binB2(
    const int* __restrict__ cnt, const int* __restrict__ bbase, const int* __restrict__ bcur,
    const u64* __restrict__ arena, int* __restrict__ rowptr, int* __restrict__ colidx,
    int N, int E) {
    __shared__ int rowL[256], lofs[256];
    int b = blockIdx.x, tid = threadIdx.x;
    int n0 = b << BSH;
    int n = n0 + tid;
    int c = (n < N) ? cnt[n] : 0;
    lofs[tid] = 0;
    if (tid < 64) {
        // placeholder to keep shape; real scan below uses all lanes via LDS
    }
    rowL[tid] = c;
    __syncthreads();
    if (tid < 64) {
        int h0 = rowL[4 * tid], h1 = rowL[4 * tid + 1];
        int h2 = rowL[4 * tid + 2], h3 = rowL[4 * tid + 3];
        int s01 = h0 + h1;
        int loc = s01 + h2 + h3;
        int inc = loc;
        #pragma unroll
        for (int off = 1; off < 64; off <<= 1) {
            int tv = __shfl_up(inc, off);
            if (tid >= off) inc += tv;
        }
        int excl = inc - loc;
        rowL[4 * tid] = excl;
        rowL[4 * tid + 1] = excl + h0;
        rowL[4 * tid + 2] = excl + s01;
        rowL[4 * tid + 3] = excl + s01 + h2;
    }
    __syncthreads();
    int base = bbase[b];
    if (n < N) rowptr[n] = base + rowL[tid];
    if (b == 0 && tid == 0) rowptr[N] = E;
    rowL[tid] += base;
    __syncthreads();
    int nedge = bcur[b];
    if (nedge > CAP) nedge = CAP;
    for (int i = tid; i < nedge; i += 256) {
        u64 pk = arena[(size_t)b * CAP + i];
        int d = (int)(pk >> 32), s = (int)(pk & 0xFFFFFFFFu);
        int slot = atomicAdd(&lofs[d - n0], 1);
        colidx[rowL[d - n0] + slot] = s;
    }
}

// ---------------- GAT linear via MFMA ----------------
__global__ __launch_bounds__(256) void k_gat_mfma(
    const u16* __restrict__ h, const u16* __restrict__ wf,
    const float* __restrict__ asrcw, const float* __restrict__ adstw,
    u16* __restrict__ hh, float* __restrict__ a_src, float* __restrict__ a_dst, int N) {
    int wv = threadIdx.x >> 6, lane = threadIdx.x & 63;
    int rowbase = blockIdx.x * 64 + wv * 16;
    if (rowbase >= N) return;
    int n16 = lane & 15, quad = lane >> 4;
    int arow = min(rowbase + n16, N - 1);
    f32x4 acc[8] = {};
    #pragma unroll
    for (int kt = 0; kt < 4; kt++) {
        bf16x8 a = *(const bf16x8*)(h + (size_t)arow * HD + kt * 32 + quad * 8);
        #pragma unroll
        for (int ct = 0; ct < 8; ct++) {
            bf16x8 b = *(const bf16x8*)(wf + ((size_t)(ct * 4 + kt) * 64 + lane) * 8);
            acc[ct] = __builtin_amdgcn_mfma_f32_16x16x32_bf16(a, b, acc[ct], 0, 0, 0);
        }
    }
    float asw[8], adw[8];
    #pragma unroll
    for (int ct = 0; ct < 8; ct++) {
        asw[ct] = asrcw[ct * 16 + n16];
        adw[ct] = adstw[ct * 16 + n16];
    }
    float ps[4][4], pd[4][4];
    #pragma unroll
    for (int hd = 0; hd < 4; hd++)
        #pragma unroll
        for (int reg = 0; reg < 4; reg++) {
            ps[hd][reg] = acc[2 * hd][reg] * asw[2 * hd] + acc[2 * hd + 1][reg] * asw[2 * hd + 1];
            pd[hd][reg] = acc[2 * hd][reg] * adw[2 * hd] + acc[2 * hd + 1][reg] * adw[2 * hd + 1];
        }
    #pragma unroll
    for (int msk = 1; msk < 16; msk <<= 1) {
        #pragma unroll
        for (int hd = 0; hd < 4; hd++)
            #pragma unroll
            for (int reg = 0; reg < 4; reg++) {
                ps[hd][reg] += __shfl_xor(ps[hd][reg], msk);
                pd[hd][reg] += __shfl_xor(pd[hd][reg], msk);
            }
    }
    #pragma unroll
    for (int reg = 0; reg < 4; reg++) {
        int row = rowbase + quad * 4 + reg;
        if (row < N) {
            #pragma unroll
            for (int ct = 0; ct < 8; ct++)
                hh[(size_t)row * HD + ct * 16 + n16] = f2b(acc[ct][reg]);
            if (n16 < 4) {
                float ws = 0.f, wd = 0.f;
                #pragma unroll
                for (int hd = 0; hd < 4; hd++)
                    if (n16 == hd) { ws = ps[hd][reg]; wd = pd[hd][reg]; }
                a_src[row * 4 + n16] = ws;
                a_dst[row * 4 + n16] = wd;
            }
        }
    }
}

// ---------------- per-node attention aggregation: 8-wide batched gather ----------------
__global__ __launch_bounds__(256) void k_agg(
    u16* __restrict__ h, const u32* __restrict__ hh32,
    const float* __restrict__ a_src, const float* __restrict__ a_dst,
    const int* __restrict__ rowptr, const int* __restrict__ colidx,
    const float* __restrict__ bias, const float* __restrict__ bng, const float* __restrict__ bnb,
    const float* __restrict__ bnm, const float* __restrict__ bnv, int N) {
    __shared__ int   sL[4][64];
    __shared__ __align__(16) float eeL[4][64][4];
    int wv = threadIdx.x >> 6, lane = threadIdx.x & 63;
    int node = blockIdx.x * 4 + wv;
    if (node >= N) return;
    int head = lane >> 4;
    const float4* as4p = (const float4*)a_src;
    float4 ad4 = ((const float4*)a_dst)[node];
    float adh = (head == 0) ? ad4.x : (head == 1) ? ad4.y : (head == 2) ? ad4.z : ad4.w;
    float ash = a_src[node * 4 + head];
    float e = ash + adh;
    e = (e > 0.f) ? e : 0.2f * e;
    float ee = __expf(e);
    float den = ee;
    u32 hv = hh32[(size_t)node * 64 + lane];
    float acc0 = ee * lo16(hv), acc1 = ee * hi16(hv);
    int beg = rowptr[node], end = rowptr[node + 1];
    for (int base = beg; base < end; base += 64) {
        int cnt = end - base; if (cnt > 64) cnt = 64;
        int s = 0;
        float4 e4 = {0.f, 0.f, 0.f, 0.f};
        if (lane < cnt) {
            s = colidx[base + lane];
            float4 as4 = as4p[s];
            float t0 = as4.x + ad4.x, t1 = as4.y + ad4.y, t2 = as4.z + ad4.z, t3 = as4.w + ad4.w;
            t0 = (t0 > 0.f) ? t0 : 0.2f * t0; t1 = (t1 > 0.f) ? t1 : 0.2f * t1;
            t2 = (t2 > 0.f) ? t2 : 0.2f * t2; t3 = (t3 > 0.f) ? t3 : 0.2f * t3;
            e4.x = __expf(t0); e4.y = __expf(t1); e4.z = __expf(t2); e4.w = __expf(t3);
        }
        sL[wv][lane] = s;
        ((float4*)eeL[wv][lane])[0] = e4;
        int j = 0;
        for (; j + 8 <= cnt; j += 8) {
            u32 hv2[8]; float w[8];
            #pragma unroll
            for (int q = 0; q < 8; q++) {
                int sj = sL[wv][j + q];
                w[q] = eeL[wv][j + q][head];
                hv2[q] = hh32[(size_t)sj * 64 + lane];
            }
            #pragma unroll
            for (int q = 0; q < 8; q++) {
                den += w[q];
                acc0 += w[q] * lo16(hv2[q]);
                acc1 += w[q] * hi16(hv2[q]);
            }
        }
        for (; j < cnt; j++) {
            int sj = sL[wv][j];
            float w = eeL[wv][j][head];
            u32 hv2 = hh32[(size_t)sj * 64 + lane];
            den += w;
            acc0 += w * lo16(hv2);
            acc1 += w * hi16(hv2);
        }
    }
    float inv = 1.0f / (den + 1e-16f);
    int c0 = lane * 2, c1 = c0 + 1;
    float o0 = acc0 * inv, o1 = acc1 * inv;
    float sc0 = bng[c0] * rsqrtf(bnv[c0] + EPS);
    float sc1 = bng[c1] * rsqrtf(bnv[c1] + EPS);
    o0 = (o0 + bias[c0] - bnm[c0]) * sc0 + bnb[c0];
    o1 = (o1 + bias[c1] - bnm[c1]) * sc1 + bnb[c1];
    o0 = fmaxf(o0, 0.f); o1 = fmaxf(o1, 0.f);
    u32 idv = ((const u32*)h)[(size_t)node * 64 + lane];
    o0 += lo16(idv); o1 += hi16(idv);
    ((u32*)h)[(size_t)node * 64 + lane] = ((u32)f2b(o1) << 16) | f2b(o0);
}

// ---------------- pooling + glob encoder -> z[G,384] f32 (R7-measured-fast) ----------------
__global__ __launch_bounds__(256) void k_pool(
    const u16* __restrict__ h, const int* __restrict__ gs,
    const float* __restrict__ gf, const float* __restrict__ glob_w, const float* __restrict__ glob_b,
    const float* __restrict__ gbg, const float* __restrict__ gbb,
    const float* __restrict__ gbm, const float* __restrict__ gbv,
    float* __restrict__ z, int N, int G) {
    __shared__ float s0L[4][64], s1L[4][64], m0L[4][64], m1L[4][64];
    int g = blockIdx.x, tid = threadIdx.x;
    int wv = tid >> 6, lane = tid & 63;
    int beg = gs[g], end = gs[g + 1];
    const u32* h32 = (const u32*)h;
    float s0 = 0.f, s1 = 0.f, m0 = -3.4e38f, m1 = -3.4e38f;
    for (int r = beg + wv; r < end; r += 4) {
        u32 pk = h32[(size_t)r * 64 + lane];
        float v0 = lo16(pk), v1 = hi16(pk);
        s0 += v0; s1 += v1;
        m0 = fmaxf(m0, v0); m1 = fmaxf(m1, v1);
    }
    s0L[wv][lane] = s0; s1L[wv][lane] = s1;
    m0L[wv][lane] = m0; m1L[wv][lane] = m1;
    __syncthreads();
    if (tid < 64) {
        float a0 = s0L[0][lane] + s0L[1][lane] + s0L[2][lane] + s0L[3][lane];
        float a1 = s1L[0][lane] + s1L[1][lane] + s1L[2][lane] + s1L[3][lane];
        float x0 = fmaxf(fmaxf(m0L[0][lane], m0L[1][lane]), fmaxf(m0L[2][lane], m0L[3][lane]));
        float x1 = fmaxf(fmaxf(m1L[0][lane], m1L[1][lane]), fmaxf(m1L[2][lane], m1L[3][lane]));
        int cnt = end - beg;
        float inv = 1.0f / (float)(cnt > 0 ? cnt : 1);
        if (cnt == 0) { x0 = 0.f; x1 = 0.f; }
        ((float2*)(z + (size_t)g * 384))[lane] = make_float2(a0 * inv, a1 * inv);
        ((float2*)(z + (size_t)g * 384 + 128))[lane] = make_float2(x0, x1);
    } else if (tid >= 128) {
        int c = tid - 128;
        float acc = glob_b[c];
        #pragma unroll 8
        for (int k = 0; k < 32; k++) acc += gf[g * 32 + k] * glob_w[k * HD + c];
        float sc = gbg[c] * rsqrtf(gbv[c] + EPS);
        acc = (acc - gbm[c]) * sc + gbb[c];
        z[(size_t)g * 384 + 256 + c] = fmaxf(acc, 0.f);
    }
}

// ---------------- lin1(+relu) . W2 + b2 with LDS-staged W1; 8 graphs/block ----------------
__global__ __launch_bounds__(256) void k_lin(
    const float* __restrict__ z, const float* __restrict__ W1, const float* __restrict__ b1,
    const float* __restrict__ W2, const float* __restrict__ b2, float* __restrict__ out, int G) {
    __shared__ float zL[8][384];    // 12 KB
    __shared__ float Wc[64][128];   // 32 KB
    __shared__ float red[8][128];   // 4 KB
    int tid = threadIdx.x;
    int g0 = blockIdx.x * 8;
    int c = tid & 127, half = tid >> 7;
    for (int i = tid; i < 8 * 384; i += 256) {
        int gi = i / 384, kk = i % 384;
        zL[gi][kk] = (g0 + gi < G) ? z[(size_t)(g0 + gi) * 384 + kk] : 0.f;
    }
    float acc0 = 0.f, acc1 = 0.f, acc2 = 0.f, acc3 = 0.f;
    int gb = half * 4;
    for (int ch = 0; ch < 6; ch++) {
        __syncthreads();
        for (int i4 = tid; i4 < 2048; i4 += 256) {
            int flat = i4 * 4;
            int k = flat >> 7, cc = flat & 127;
            *(float4*)&Wc[k][cc] = *(const float4*)&W1[(size_t)(ch * 64 + k) * HD + cc];
        }
        __syncthreads();
        int kb = ch * 64;
        #pragma unroll 4
        for (int k = 0; k < 64; k++) {
            float w = Wc[k][c];
            acc0 += zL[gb + 0][kb + k] * w;
            acc1 += zL[gb + 1][kb + k] * w;
            acc2 += zL[gb + 2][kb + k] * w;
            acc3 += zL[gb + 3][kb + k] * w;
        }
    }
    float b1c = b1[c], w2c = W2[c];
    __syncthreads();
    red[gb + 0][c] = fmaxf(acc0 + b1c, 0.f) * w2c;
    red[gb + 1][c] = fmaxf(acc1 + b1c, 0.f) * w2c;
    red[gb + 2][c] = fmaxf(acc2 + b1c, 0.f) * w2c;
    red[gb + 3][c] = fmaxf(acc3 + b1c, 0.f) * w2c;
    __syncthreads();
    int gr = tid >> 5, l32 = tid & 31;
    float v = red[gr][l32] + red[gr][l32 + 32] + red[gr][l32 + 64] + red[gr][l32 + 96];
    #pragma unroll
    for (int m = 1; m < 32; m <<= 1) v += __shfl_xor(v, m, 32);
    if (l32 == 0 && g0 + gr < G) out[g0 + gr] = v + b2[0];
}

extern "C" void kernel_launch(void* const* d_in, const int* in_sizes, int n_in,
                              void* d_out, int out_size, void* d_ws, size_t ws_size,
                              hipStream_t stream) {
    (void)n_in; (void)out_size; (void)ws_size;
    const float* x        = (const float*)d_in[0];
    const float* gfeat    = (const float*)d_in[2];
    const int*   ei       = (const int*)d_in[3];
    const int*   batch    = (const int*)d_in[4];
    const float* node_w   = (const float*)d_in[5];
    const float* node_b   = (const float*)d_in[6];
    const float* nbg      = (const float*)d_in[7];
    const float* nbb      = (const float*)d_in[8];
    const float* nbm      = (const float*)d_in[9];
    const float* nbv      = (const float*)d_in[10];
    const float* glob_w   = (const float*)d_in[13];
    const float* glob_b   = (const float*)d_in[14];
    const float* gbg      = (const float*)d_in[15];
    const float* gbb      = (const float*)d_in[16];
    const float* gbm      = (const float*)d_in[17];
    const float* gbv      = (const float*)d_in[18];
    const float* gat_lin  = (const float*)d_in[19];
    const float* gat_asrc = (const float*)d_in[20];
    const float* gat_adst = (const float*)d_in[21];
    const float* gat_bias = (const float*)d_in[22];
    const float* bn_g     = (const float*)d_in[23];
    const float* bn_b     = (const float*)d_in[24];
    const float* bn_m     = (const float*)d_in[25];
    const float* bn_v     = (const float*)d_in[26];
    const float* lin1_w   = (const float*)d_in[27];
    const float* lin1_b   = (const float*)d_in[28];
    const float* lin2_w   = (const float*)d_in[29];
    const float* lin2_b   = (const float*)d_in[30];

    const int N = in_sizes[0] / FD;
    const int E = in_sizes[3] / 2;
    const int G = in_sizes[2] / 32;
    const int* srcp = ei;
    const int* dstp = ei + E;
    const int NB = (N + 255) >> BSH;          // 196 (<= 256 required)
    const int numTiles = (E + 4095) / 4096;   // 196

    char* p = (char*)d_ws;
    auto alloc = [&](size_t bytes) -> char* {
        char* r = p;
        p += (bytes + 255) & ~(size_t)255;
        return r;
    };
    u16*   h       = (u16*)alloc((size_t)N * HD * 2);
    u16*   hh      = (u16*)alloc((size_t)N * HD * 2);
    float* a_src   = (float*)alloc((size_t)N * 4 * 4);
    float* a_dst   = (float*)alloc((size_t)N * 4 * 4);
    int*   rowptr  = (int*)alloc((size_t)(N + 1) * 4);
    char*  zbase   = p;                        // cnt + bcur zeroed by k_prep
    int*   cnt     = (int*)alloc((size_t)N * 4);
    int*   bcur    = (int*)alloc(256 * 4);
    int    zn      = (int)((p - zbase) / 4);
    int*   bbase   = (int*)alloc(256 * 4);
    u64*   arena   = (u64*)alloc((size_t)NB * CAP * 8);
    int*   colidx  = (int*)alloc((size_t)E * 4);
    u16*   wf_node = (u16*)alloc((size_t)FD * HD * 2);
    u16*   wf_gat  = (u16*)alloc((size_t)3 * HD * HD * 2);
    float* z       = (float*)alloc((size_t)G * 384 * 4);
    int*   gs      = (int*)alloc((size_t)(G + 1) * 4);

    int SB = (N + 255) / 256;   // 196

    // D1: weight prep + graph bounds + zeroing
    k_prep<<<dim3(SB, 6), 256, 0, stream>>>(node_w, gat_lin, wf_node, wf_gat,
                                            batch, gs, (int*)zbase, zn, N, G);
    // D2: bucket-sort edges (+hist) ∪ node encoder
    int nodeBlocks = (N + 63) / 64;
    k_binA_node<<<numTiles + nodeBlocks, 256, 0, stream>>>(
        srcp, dstp, cnt, bcur, arena,
        x, wf_node, node_b, nbg, nbb, nbm, nbv, h,
        E, NB, numTiles, N);
    // D3: single-block bucket-total scan (bcur totals already known from binA)
    k_scanS<<<1, 256, 0, stream>>>(bcur, bbase, NB);
    // D4: per-bucket node scan + rowptr + scatter (fully parallel, no lookback)
    k_binB2<<<NB, 256, 0, stream>>>(cnt, bbase, bcur, arena, rowptr, colidx, N, E);

    // D5-D10: GAT layers
    for (int i = 0; i < 3; i++) {
        k_gat_mfma<<<(N + 63) / 64, 256, 0, stream>>>(
            h, wf_gat + (size_t)i * HD * HD,
            gat_asrc + i * HD, gat_adst + i * HD,
            hh, a_src, a_dst, N);
        k_agg<<<(N + 3) / 4, 256, 0, stream>>>(
            h, (const u32*)hh, a_src, a_dst, rowptr, colidx,
            gat_bias + i * HD, bn_g + i * HD, bn_b + i * HD, bn_m + i * HD, bn_v + i * HD, N);
    }

    // D11-D12: readout (512-block pool proven fast in R7, then small lin)
    k_pool<<<G, 256, 0, stream>>>(h, gs, gfeat, glob_w, glob_b, gbg, gbb, gbm, gbv, z, N, G);
    k_lin<<<(G + 7) / 8, 256, 0, stream>>>(z, lin1_w, lin1_b, lin2_w, lin2_b, (float*)d_out, G);
}

// Round 10
// 387.467 us; speedup vs baseline: 1.8223x; 1.0403x over previous
//
#include <hip/hip_runtime.h>
#include <hip/hip_bf16.h>

typedef unsigned short u16;
typedef unsigned int   u32;
typedef unsigned long long u64;

// N=50000, F=64, H=128, HEADS=4, C=32, L=3, E=800000, G=512, DG=32, NC=1
// Float I/O is FLOAT32; internal node features h/hh are bf16 for MFMA.
#define HD 128
#define FD 64
#define EPS 1e-5f
#define BSH 8
#define CAP 8192    // per-bucket arena capacity (bucket mean ~4082, max ~4350)
#define TILE 2048   // edges per binA tile (391 tile-blocks -> short critical path)

using bf16x8 = __attribute__((ext_vector_type(8))) short;
using f32x4  = __attribute__((ext_vector_type(4))) float;

__device__ __forceinline__ float b2f(u16 v) { return __uint_as_float(((u32)v) << 16); }
__device__ __forceinline__ u16 f2b(float f) {
    u32 u = __float_as_uint(f);
    return (u16)((u + 0x7FFF + ((u >> 16) & 1)) >> 16);  // RNE
}
__device__ __forceinline__ float lo16(u32 u) { return __uint_as_float(u << 16); }
__device__ __forceinline__ float hi16(u32 u) { return __uint_as_float(u & 0xFFFF0000u); }

// ---------------- prep: wprep (y<4) + gbound (y==4) + zeroing (y==5) ----------------
__global__ __launch_bounds__(256) void k_prep(
    const float* __restrict__ node_w, const float* __restrict__ gat_lin,
    u16* __restrict__ wf_node, u16* __restrict__ wf_gat,
    const int* __restrict__ batch, int* __restrict__ gs,
    int* __restrict__ zbase, int zn, int N, int G) {
    int y = blockIdx.y;
    int tid = threadIdx.x;
    if (y < 4) {
        const float* src; u16* dst; int K;
        if (y == 0) { src = node_w; dst = wf_node; K = FD; }
        else { src = gat_lin + (size_t)(y - 1) * HD * HD; dst = wf_gat + (size_t)(y - 1) * HD * HD; K = HD; }
        int KT = K >> 5;
        int total = K * HD;
        for (int f = blockIdx.x * 256 + tid; f < total; f += gridDim.x * 256) {
            int j = f & 7;
            int lane = (f >> 3) & 63;
            int t = f >> 9;           // ct*KT + kt
            int kt = t % KT;
            int ct = t / KT;
            int k = kt * 32 + (lane >> 4) * 8 + j;
            int col = ct * 16 + (lane & 15);
            dst[f] = f2b(src[k * HD + col]);
        }
    } else if (y == 4) {
        int i = blockIdx.x * 256 + tid;
        if (i < N) {
            int b = batch[i];
            if (i == 0) { for (int g = 0; g <= b; g++) gs[g] = 0; }
            else {
                int pb = batch[i - 1];
                for (int g = pb + 1; g <= b; g++) gs[g] = i;
            }
            if (i == N - 1) { for (int g = b + 1; g <= G; g++) gs[g] = N; }
        }
    } else {
        for (int i = blockIdx.x * 256 + tid; i < zn; i += gridDim.x * 256) zbase[i] = 0;
    }
}

// ---------------- binA (bucket-sort into arena; NO per-edge global atomics) ∪ node MFMA ----
__global__ __launch_bounds__(256) void k_binA_node(
    const int* __restrict__ src, const int* __restrict__ dst,
    int* __restrict__ bcur, u64* __restrict__ arena,
    const float* __restrict__ x, const u16* __restrict__ wf, const float* __restrict__ bias,
    const float* __restrict__ g, const float* __restrict__ bb, const float* __restrict__ m,
    const float* __restrict__ v, u16* __restrict__ h,
    int E, int NB, int numTiles, int N) {
    __shared__ __align__(16) char smem[TILE * 8 + 4 * 256 * 4];   // 20 KB
    int tid = threadIdx.x;
    if ((int)blockIdx.x < numTiles) {
        u32* os   = (u32*)smem;
        u32* od   = os + TILE;
        int* hist = (int*)(od + TILE);
        int* obas = hist + 256;
        int* ofs  = obas + 256;
        int* gpos = ofs + 256;
        int base = blockIdx.x * TILE;
        int cntE = E - base; if (cntE > TILE) cntE = TILE;
        hist[tid] = 0;
        __syncthreads();
        u32 rs[TILE / 256], rd[TILE / 256];
        #pragma unroll
        for (int r = 0; r < TILE / 256; r++) {
            int li = r * 256 + tid;
            if (li < cntE) {
                rs[r] = src[base + li];
                rd[r] = dst[base + li];
                atomicAdd(&hist[rd[r] >> BSH], 1);
            }
        }
        __syncthreads();
        if (tid < 64) {
            int h0 = hist[4 * tid], h1 = hist[4 * tid + 1];
            int h2 = hist[4 * tid + 2], h3 = hist[4 * tid + 3];
            int s01 = h0 + h1;
            int loc = s01 + h2 + h3;
            int inc = loc;
            #pragma unroll
            for (int off = 1; off < 64; off <<= 1) {
                int tv = __shfl_up(inc, off);
                if (tid >= off) inc += tv;
            }
            int excl = inc - loc;
            obas[4 * tid] = excl;                 ofs[4 * tid] = excl;
            obas[4 * tid + 1] = excl + h0;        ofs[4 * tid + 1] = excl + h0;
            obas[4 * tid + 2] = excl + s01;       ofs[4 * tid + 2] = excl + s01;
            obas[4 * tid + 3] = excl + s01 + h2;  ofs[4 * tid + 3] = excl + s01 + h2;
        }
        __syncthreads();
        #pragma unroll
        for (int r = 0; r < TILE / 256; r++) {
            int li = r * 256 + tid;
            if (li < cntE) {
                int b = rd[r] >> BSH;
                int posn = atomicAdd(&ofs[b], 1);
                os[posn] = rs[r];
                od[posn] = rd[r];
            }
        }
        __syncthreads();
        if (tid < NB && hist[tid] > 0)
            gpos[tid] = atomicAdd(&bcur[tid], hist[tid]);
        __syncthreads();
        for (int li = tid; li < cntE; li += 256) {
            u32 d = od[li];
            int b = d >> BSH;
            int p = gpos[b] + (li - obas[b]);
            if (p < CAP) arena[(size_t)b * CAP + p] = ((u64)d << 32) | os[li];
        }
    } else {
        // ---- node encoder: h = relu(bn(x @ W + b)) via MFMA ----
        int nb = blockIdx.x - numTiles;
        int wv = tid >> 6, lane = tid & 63;
        int rowbase = nb * 64 + wv * 16;
        if (rowbase >= N) return;
        int n16 = lane & 15, quad = lane >> 4;
        int arow = min(rowbase + n16, N - 1);
        f32x4 acc[8] = {};
        #pragma unroll
        for (int kt = 0; kt < 2; kt++) {
            const float4* xp = (const float4*)(x + (size_t)arow * FD + kt * 32 + quad * 8);
            float4 a0 = xp[0], a1 = xp[1];
            bf16x8 a;
            a[0] = (short)f2b(a0.x); a[1] = (short)f2b(a0.y);
            a[2] = (short)f2b(a0.z); a[3] = (short)f2b(a0.w);
            a[4] = (short)f2b(a1.x); a[5] = (short)f2b(a1.y);
            a[6] = (short)f2b(a1.z); a[7] = (short)f2b(a1.w);
            #pragma unroll
            for (int ct = 0; ct < 8; ct++) {
                bf16x8 b = *(const bf16x8*)(wf + ((size_t)(ct * 2 + kt) * 64 + lane) * 8);
                acc[ct] = __builtin_amdgcn_mfma_f32_16x16x32_bf16(a, b, acc[ct], 0, 0, 0);
            }
        }
        #pragma unroll
        for (int ct = 0; ct < 8; ct++) {
            int col = ct * 16 + n16;
            float sc = g[col] * rsqrtf(v[col] + EPS);
            float bi = (bias[col] - m[col]) * sc + bb[col];
            #pragma unroll
            for (int reg = 0; reg < 4; reg++) {
                int row = rowbase + quad * 4 + reg;
                if (row < N) h[(size_t)row * HD + col] = f2b(fmaxf(acc[ct][reg] * sc + bi, 0.f));
            }
        }
    }
}

// ---------------- single-block scan of bucket totals (bcur -> bbase) ----------------
__global__ __launch_bounds__(256) void k_scanS(const int* __restrict__ bcur, int* __restrict__ bbase, int NB) {
    __shared__ int s[256];
    int tid = threadIdx.x;
    int v = (tid < NB) ? bcur[tid] : 0;
    s[tid] = v;
    __syncthreads();
    for (int off = 1; off < 256; off <<= 1) {
        int t = (tid >= off) ? s[tid - off] : 0;
        __syncthreads();
        s[tid] += t;
        __syncthreads();
    }
    if (tid < NB) bbase[tid] = s[tid] - v;   // exclusive
}

// ---------------- per-bucket: count (from arena) + scan -> rowptr + scatter -> colidx ------
__global__ __launch_bounds__(256) void k_binB2(
    const int* __restrict__ bbase, const int* __restrict__ bcur,
    const u64* __restrict__ arena, int* __restrict__ rowptr, int* __restrict__ colidx,
    int N, int E) {
    __shared__ int rowL[256], lofs[256];
    int b = blockIdx.x, tid = threadIdx.x;
    int n0 = b << BSH;
    int n = n0 + tid;
    int nedge = bcur[b];
    if (nedge > CAP) nedge = CAP;
    lofs[tid] = 0;
    __syncthreads();
    // pass 1: per-node counts from the arena window (LDS atomics)
    for (int i = tid; i < nedge; i += 256) {
        int d = (int)(arena[(size_t)b * CAP + i] >> 32);
        atomicAdd(&lofs[d - n0], 1);
    }
    __syncthreads();
    rowL[tid] = lofs[tid];
    __syncthreads();
    if (tid < 64) {
        int h0 = rowL[4 * tid], h1 = rowL[4 * tid + 1];
        int h2 = rowL[4 * tid + 2], h3 = rowL[4 * tid + 3];
        int s01 = h0 + h1;
        int loc = s01 + h2 + h3;
        int inc = loc;
        #pragma unroll
        for (int off = 1; off < 64; off <<= 1) {
            int tv = __shfl_up(inc, off);
            if (tid >= off) inc += tv;
        }
        int excl = inc - loc;
        rowL[4 * tid] = excl;
        rowL[4 * tid + 1] = excl + h0;
        rowL[4 * tid + 2] = excl + s01;
        rowL[4 * tid + 3] = excl + s01 + h2;
    }
    __syncthreads();
    int base = bbase[b];
    if (n < N) rowptr[n] = base + rowL[tid];
    if (b == 0 && tid == 0) rowptr[N] = E;
    rowL[tid] += base;
    lofs[tid] = 0;
    __syncthreads();
    // pass 2: scatter
    for (int i = tid; i < nedge; i += 256) {
        u64 pk = arena[(size_t)b * CAP + i];
        int d = (int)(pk >> 32), s = (int)(pk & 0xFFFFFFFFu);
        int slot = atomicAdd(&lofs[d - n0], 1);
        colidx[rowL[d - n0] + slot] = s;
    }
}

// ---------------- GAT linear via MFMA ----------------
__global__ __launch_bounds__(256) void k_gat_mfma(
    const u16* __restrict__ h, const u16* __restrict__ wf,
    const float* __restrict__ asrcw, const float* __restrict__ adstw,
    u16* __restrict__ hh, float* __restrict__ a_src, float* __restrict__ a_dst, int N) {
    int wv = threadIdx.x >> 6, lane = threadIdx.x & 63;
    int rowbase = blockIdx.x * 64 + wv * 16;
    if (rowbase >= N) return;
    int n16 = lane & 15, quad = lane >> 4;
    int arow = min(rowbase + n16, N - 1);
    f32x4 acc[8] = {};
    #pragma unroll
    for (int kt = 0; kt < 4; kt++) {
        bf16x8 a = *(const bf16x8*)(h + (size_t)arow * HD + kt * 32 + quad * 8);
        #pragma unroll
        for (int ct = 0; ct < 8; ct++) {
            bf16x8 b = *(const bf16x8*)(wf + ((size_t)(ct * 4 + kt) * 64 + lane) * 8);
            acc[ct] = __builtin_amdgcn_mfma_f32_16x16x32_bf16(a, b, acc[ct], 0, 0, 0);
        }
    }
    float asw[8], adw[8];
    #pragma unroll
    for (int ct = 0; ct < 8; ct++) {
        asw[ct] = asrcw[ct * 16 + n16];
        adw[ct] = adstw[ct * 16 + n16];
    }
    float ps[4][4], pd[4][4];
    #pragma unroll
    for (int hd = 0; hd < 4; hd++)
        #pragma unroll
        for (int reg = 0; reg < 4; reg++) {
            ps[hd][reg] = acc[2 * hd][reg] * asw[2 * hd] + acc[2 * hd + 1][reg] * asw[2 * hd + 1];
            pd[hd][reg] = acc[2 * hd][reg] * adw[2 * hd] + acc[2 * hd + 1][reg] * adw[2 * hd + 1];
        }
    #pragma unroll
    for (int msk = 1; msk < 16; msk <<= 1) {
        #pragma unroll
        for (int hd = 0; hd < 4; hd++)
            #pragma unroll
            for (int reg = 0; reg < 4; reg++) {
                ps[hd][reg] += __shfl_xor(ps[hd][reg], msk);
                pd[hd][reg] += __shfl_xor(pd[hd][reg], msk);
            }
    }
    #pragma unroll
    for (int reg = 0; reg < 4; reg++) {
        int row = rowbase + quad * 4 + reg;
        if (row < N) {
            #pragma unroll
            for (int ct = 0; ct < 8; ct++)
                hh[(size_t)row * HD + ct * 16 + n16] = f2b(acc[ct][reg]);
            if (n16 < 4) {
                float ws = 0.f, wd = 0.f;
                #pragma unroll
                for (int hd = 0; hd < 4; hd++)
                    if (n16 == hd) { ws = ps[hd][reg]; wd = pd[hd][reg]; }
                a_src[row * 4 + n16] = ws;
                a_dst[row * 4 + n16] = wd;
            }
        }
    }
}

// ---------------- per-node attention aggregation: 8-wide batched gather ----------------
__global__ __launch_bounds__(256) void k_agg(
    u16* __restrict__ h, const u32* __restrict__ hh32,
    const float* __restrict__ a_src, const float* __restrict__ a_dst,
    const int* __restrict__ rowptr, const int* __restrict__ colidx,
    const float* __restrict__ bias, const float* __restrict__ bng, const float* __restrict__ bnb,
    const float* __restrict__ bnm, const float* __restrict__ bnv, int N) {
    __shared__ int   sL[4][64];
    __shared__ __align__(16) float eeL[4][64][4];
    int wv = threadIdx.x >> 6, lane = threadIdx.x & 63;
    int node = blockIdx.x * 4 + wv;
    if (node >= N) return;
    int head = lane >> 4;
    const float4* as4p = (const float4*)a_src;
    float4 ad4 = ((const float4*)a_dst)[node];
    float adh = (head == 0) ? ad4.x : (head == 1) ? ad4.y : (head == 2) ? ad4.z : ad4.w;
    float ash = a_src[node * 4 + head];
    float e = ash + adh;
    e = (e > 0.f) ? e : 0.2f * e;
    float ee = __expf(e);
    float den = ee;
    u32 hv = hh32[(size_t)node * 64 + lane];
    float acc0 = ee * lo16(hv), acc1 = ee * hi16(hv);
    int beg = rowptr[node], end = rowptr[node + 1];
    for (int base = beg; base < end; base += 64) {
        int cnt = end - base; if (cnt > 64) cnt = 64;
        int s = 0;
        float4 e4 = {0.f, 0.f, 0.f, 0.f};
        if (lane < cnt) {
            s = colidx[base + lane];
            float4 as4 = as4p[s];
            float t0 = as4.x + ad4.x, t1 = as4.y + ad4.y, t2 = as4.z + ad4.z, t3 = as4.w + ad4.w;
            t0 = (t0 > 0.f) ? t0 : 0.2f * t0; t1 = (t1 > 0.f) ? t1 : 0.2f * t1;
            t2 = (t2 > 0.f) ? t2 : 0.2f * t2; t3 = (t3 > 0.f) ? t3 : 0.2f * t3;
            e4.x = __expf(t0); e4.y = __expf(t1); e4.z = __expf(t2); e4.w = __expf(t3);
        }
        sL[wv][lane] = s;
        ((float4*)eeL[wv][lane])[0] = e4;
        int j = 0;
        for (; j + 8 <= cnt; j += 8) {
            u32 hv2[8]; float w[8];
            #pragma unroll
            for (int q = 0; q < 8; q++) {
                int sj = sL[wv][j + q];
                w[q] = eeL[wv][j + q][head];
                hv2[q] = hh32[(size_t)sj * 64 + lane];
            }
            #pragma unroll
            for (int q = 0; q < 8; q++) {
                den += w[q];
                acc0 += w[q] * lo16(hv2[q]);
                acc1 += w[q] * hi16(hv2[q]);
            }
        }
        for (; j < cnt; j++) {
            int sj = sL[wv][j];
            float w = eeL[wv][j][head];
            u32 hv2 = hh32[(size_t)sj * 64 + lane];
            den += w;
            acc0 += w * lo16(hv2);
            acc1 += w * hi16(hv2);
        }
    }
    float inv = 1.0f / (den + 1e-16f);
    int c0 = lane * 2, c1 = c0 + 1;
    float o0 = acc0 * inv, o1 = acc1 * inv;
    float sc0 = bng[c0] * rsqrtf(bnv[c0] + EPS);
    float sc1 = bng[c1] * rsqrtf(bnv[c1] + EPS);
    o0 = (o0 + bias[c0] - bnm[c0]) * sc0 + bnb[c0];
    o1 = (o1 + bias[c1] - bnm[c1]) * sc1 + bnb[c1];
    o0 = fmaxf(o0, 0.f); o1 = fmaxf(o1, 0.f);
    u32 idv = ((const u32*)h)[(size_t)node * 64 + lane];
    o0 += lo16(idv); o1 += hi16(idv);
    ((u32*)h)[(size_t)node * 64 + lane] = ((u32)f2b(o1) << 16) | f2b(o0);
}

// ---------------- pooling + glob encoder -> z[G,384] f32 ----------------
__global__ __launch_bounds__(256) void k_pool(
    const u16* __restrict__ h, const int* __restrict__ gs,
    const float* __restrict__ gf, const float* __restrict__ glob_w, const float* __restrict__ glob_b,
    const float* __restrict__ gbg, const float* __restrict__ gbb,
    const float* __restrict__ gbm, const float* __restrict__ gbv,
    float* __restrict__ z, int N, int G) {
    __shared__ float s0L[4][64], s1L[4][64], m0L[4][64], m1L[4][64];
    int g = blockIdx.x, tid = threadIdx.x;
    int wv = tid >> 6, lane = tid & 63;
    int beg = gs[g], end = gs[g + 1];
    const u32* h32 = (const u32*)h;
    float s0 = 0.f, s1 = 0.f, m0 = -3.4e38f, m1 = -3.4e38f;
    for (int r = beg + wv; r < end; r += 4) {
        u32 pk = h32[(size_t)r * 64 + lane];
        float v0 = lo16(pk), v1 = hi16(pk);
        s0 += v0; s1 += v1;
        m0 = fmaxf(m0, v0); m1 = fmaxf(m1, v1);
    }
    s0L[wv][lane] = s0; s1L[wv][lane] = s1;
    m0L[wv][lane] = m0; m1L[wv][lane] = m1;
    __syncthreads();
    if (tid < 64) {
        float a0 = s0L[0][lane] + s0L[1][lane] + s0L[2][lane] + s0L[3][lane];
        float a1 = s1L[0][lane] + s1L[1][lane] + s1L[2][lane] + s1L[3][lane];
        float x0 = fmaxf(fmaxf(m0L[0][lane], m0L[1][lane]), fmaxf(m0L[2][lane], m0L[3][lane]));
        float x1 = fmaxf(fmaxf(m1L[0][lane], m1L[1][lane]), fmaxf(m1L[2][lane], m1L[3][lane]));
        int cnt = end - beg;
        float inv = 1.0f / (float)(cnt > 0 ? cnt : 1);
        if (cnt == 0) { x0 = 0.f; x1 = 0.f; }
        ((float2*)(z + (size_t)g * 384))[lane] = make_float2(a0 * inv, a1 * inv);
        ((float2*)(z + (size_t)g * 384 + 128))[lane] = make_float2(x0, x1);
    } else if (tid >= 128) {
        int c = tid - 128;
        float acc = glob_b[c];
        #pragma unroll 8
        for (int k = 0; k < 32; k++) acc += gf[g * 32 + k] * glob_w[k * HD + c];
        float sc = gbg[c] * rsqrtf(gbv[c] + EPS);
        acc = (acc - gbm[c]) * sc + gbb[c];
        z[(size_t)g * 384 + 256 + c] = fmaxf(acc, 0.f);
    }
}

// ---------------- lin1(+relu) . W2 + b2 with LDS-staged W1; 8 graphs/block ----------------
__global__ __launch_bounds__(256) void k_lin(
    const float* __restrict__ z, const float* __restrict__ W1, const float* __restrict__ b1,
    const float* __restrict__ W2, const float* __restrict__ b2, float* __restrict__ out, int G) {
    __shared__ float zL[8][384];    // 12 KB
    __shared__ float Wc[64][128];   // 32 KB
    __shared__ float red[8][128];   // 4 KB
    int tid = threadIdx.x;
    int g0 = blockIdx.x * 8;
    int c = tid & 127, half = tid >> 7;
    for (int i = tid; i < 8 * 384; i += 256) {
        int gi = i / 384, kk = i % 384;
        zL[gi][kk] = (g0 + gi < G) ? z[(size_t)(g0 + gi) * 384 + kk] : 0.f;
    }
    float acc0 = 0.f, acc1 = 0.f, acc2 = 0.f, acc3 = 0.f;
    int gb = half * 4;
    for (int ch = 0; ch < 6; ch++) {
        __syncthreads();
        for (int i4 = tid; i4 < 2048; i4 += 256) {
            int flat = i4 * 4;
            int k = flat >> 7, cc = flat & 127;
            *(float4*)&Wc[k][cc] = *(const float4*)&W1[(size_t)(ch * 64 + k) * HD + cc];
        }
        __syncthreads();
        int kb = ch * 64;
        #pragma unroll 4
        for (int k = 0; k < 64; k++) {
            float w = Wc[k][c];
            acc0 += zL[gb + 0][kb + k] * w;
            acc1 += zL[gb + 1][kb + k] * w;
            acc2 += zL[gb + 2][kb + k] * w;
            acc3 += zL[gb + 3][kb + k] * w;
        }
    }
    float b1c = b1[c], w2c = W2[c];
    __syncthreads();
    red[gb + 0][c] = fmaxf(acc0 + b1c, 0.f) * w2c;
    red[gb + 1][c] = fmaxf(acc1 + b1c, 0.f) * w2c;
    red[gb + 2][c] = fmaxf(acc2 + b1c, 0.f) * w2c;
    red[gb + 3][c] = fmaxf(acc3 + b1c, 0.f) * w2c;
    __syncthreads();
    int gr = tid >> 5, l32 = tid & 31;
    float v = red[gr][l32] + red[gr][l32 + 32] + red[gr][l32 + 64] + red[gr][l32 + 96];
    #pragma unroll
    for (int m = 1; m < 32; m <<= 1) v += __shfl_xor(v, m, 32);
    if (l32 == 0 && g0 + gr < G) out[g0 + gr] = v + b2[0];
}

extern "C" void kernel_launch(void* const* d_in, const int* in_sizes, int n_in,
                              void* d_out, int out_size, void* d_ws, size_t ws_size,
                              hipStream_t stream) {
    (void)n_in; (void)out_size; (void)ws_size;
    const float* x        = (const float*)d_in[0];
    const float* gfeat    = (const float*)d_in[2];
    const int*   ei       = (const int*)d_in[3];
    const int*   batch    = (const int*)d_in[4];
    const float* node_w   = (const float*)d_in[5];
    const float* node_b   = (const float*)d_in[6];
    const float* nbg      = (const float*)d_in[7];
    const float* nbb      = (const float*)d_in[8];
    const float* nbm      = (const float*)d_in[9];
    const float* nbv      = (const float*)d_in[10];
    const float* glob_w   = (const float*)d_in[13];
    const float* glob_b   = (const float*)d_in[14];
    const float* gbg      = (const float*)d_in[15];
    const float* gbb      = (const float*)d_in[16];
    const float* gbm      = (const float*)d_in[17];
    const float* gbv      = (const float*)d_in[18];
    const float* gat_lin  = (const float*)d_in[19];
    const float* gat_asrc = (const float*)d_in[20];
    const float* gat_adst = (const float*)d_in[21];
    const float* gat_bias = (const float*)d_in[22];
    const float* bn_g     = (const float*)d_in[23];
    const float* bn_b     = (const float*)d_in[24];
    const float* bn_m     = (const float*)d_in[25];
    const float* bn_v     = (const float*)d_in[26];
    const float* lin1_w   = (const float*)d_in[27];
    const float* lin1_b   = (const float*)d_in[28];
    const float* lin2_w   = (const float*)d_in[29];
    const float* lin2_b   = (const float*)d_in[30];

    const int N = in_sizes[0] / FD;
    const int E = in_sizes[3] / 2;
    const int G = in_sizes[2] / 32;
    const int* srcp = ei;
    const int* dstp = ei + E;
    const int NB = (N + 255) >> BSH;            // 196 (<= 256 required)
    const int numTiles = (E + TILE - 1) / TILE; // 391

    char* p = (char*)d_ws;
    auto alloc = [&](size_t bytes) -> char* {
        char* r = p;
        p += (bytes + 255) & ~(size_t)255;
        return r;
    };
    u16*   h       = (u16*)alloc((size_t)N * HD * 2);
    u16*   hh      = (u16*)alloc((size_t)N * HD * 2);
    float* a_src   = (float*)alloc((size_t)N * 4 * 4);
    float* a_dst   = (float*)alloc((size_t)N * 4 * 4);
    int*   rowptr  = (int*)alloc((size_t)(N + 1) * 4);
    char*  zbase   = p;                        // bcur zeroed by k_prep
    int*   bcur    = (int*)alloc(256 * 4);
    int    zn      = (int)((p - zbase) / 4);
    int*   bbase   = (int*)alloc(256 * 4);
    u64*   arena   = (u64*)alloc((size_t)NB * CAP * 8);
    int*   colidx  = (int*)alloc((size_t)E * 4);
    u16*   wf_node = (u16*)alloc((size_t)FD * HD * 2);
    u16*   wf_gat  = (u16*)alloc((size_t)3 * HD * HD * 2);
    float* z       = (float*)alloc((size_t)G * 384 * 4);
    int*   gs      = (int*)alloc((size_t)(G + 1) * 4);

    int SB = (N + 255) / 256;   // 196

    // D1: weight prep + graph bounds + zeroing
    k_prep<<<dim3(SB, 6), 256, 0, stream>>>(node_w, gat_lin, wf_node, wf_gat,
                                            batch, gs, (int*)zbase, zn, N, G);
    // D2: bucket-sort edges ∪ node encoder
    int nodeBlocks = (N + 63) / 64;
    k_binA_node<<<numTiles + nodeBlocks, 256, 0, stream>>>(
        srcp, dstp, bcur, arena,
        x, wf_node, node_b, nbg, nbb, nbm, nbv, h,
        E, NB, numTiles, N);
    // D3: single-block bucket-total scan
    k_scanS<<<1, 256, 0, stream>>>(bcur, bbase, NB);
    // D4: per-bucket count+scan+rowptr+scatter (fully parallel)
    k_binB2<<<NB, 256, 0, stream>>>(bbase, bcur, arena, rowptr, colidx, N, E);

    // D5-D10: GAT layers
    for (int i = 0; i < 3; i++) {
        k_gat_mfma<<<(N + 63) / 64, 256, 0, stream>>>(
            h, wf_gat + (size_t)i * HD * HD,
            gat_asrc + i * HD, gat_adst + i * HD,
            hh, a_src, a_dst, N);
        k_agg<<<(N + 3) / 4, 256, 0, stream>>>(
            h, (const u32*)hh, a_src, a_dst, rowptr, colidx,
            gat_bias + i * HD, bn_g + i * HD, bn_b + i * HD, bn_m + i * HD, bn_v + i * HD, N);
    }

    // D11-D12: readout
    k_pool<<<G, 256, 0, stream>>>(h, gs, gfeat, glob_w, glob_b, gbg, gbb, gbm, gbv, z, N, G);
    k_lin<<<(G + 7) / 8, 256, 0, stream>>>(z, lin1_w, lin1_b, lin2_w, lin2_b, (float*)d_out, G);
}